// Round 2
// baseline (161.373 us; speedup 1.0000x reference)
//
#include <hip/hip_runtime.h>
#include <stdint.h>

#define MROWS 8192
#define KDIM  512

typedef __attribute__((ext_vector_type(8))) short short8;
typedef __attribute__((ext_vector_type(4))) float f32x4;

#if __has_builtin(__builtin_amdgcn_exp2f)
#define EXP2F(x) __builtin_amdgcn_exp2f(x)
#else
#define EXP2F(x) exp2f(x)
#endif

#define GL2LDS(gp, lp) __builtin_amdgcn_global_load_lds( \
    (__attribute__((address_space(1))) void*)(gp),       \
    (__attribute__((address_space(3))) void*)(lp), 16, 0, 0)

__device__ inline unsigned short f2bf_rne(float f) {
  unsigned u = __builtin_bit_cast(unsigned, f);
  unsigned r = 0x7FFFu + ((u >> 16) & 1u);
  return (unsigned short)((u + r) >> 16);
}

// ---------------------------------------------------------------------------
// Kernel 1: cast X (fp32 -> bf16 in ws), per-row squared norm, and
// deterministic block-partial reductions for sigma^2 (column sums + sum of sq).
// ---------------------------------------------------------------------------
__global__ __launch_bounds__(256) void k_prep(
    const float* __restrict__ X, unsigned short* __restrict__ Xb,
    float* __restrict__ sq, float* __restrict__ svec_part,
    float* __restrict__ sumsq_part) {
  __shared__ float ssv[4][512];
  __shared__ float ssq[4];
  const int tid = threadIdx.x, lane = tid & 63, w = tid >> 6;
  const int b = blockIdx.x;

  float ca[8] = {0.f, 0.f, 0.f, 0.f, 0.f, 0.f, 0.f, 0.f};
  float lss = 0.f;

  for (int rr = 0; rr < 16; ++rr) {
    const int row = b * 64 + w * 16 + rr;
    const float4* xr = (const float4*)(X + (size_t)row * KDIM);
    float4 v0 = xr[lane];
    float4 v1 = xr[64 + lane];

    ushort4 p0, p1;
    p0.x = f2bf_rne(v0.x); p0.y = f2bf_rne(v0.y);
    p0.z = f2bf_rne(v0.z); p0.w = f2bf_rne(v0.w);
    p1.x = f2bf_rne(v1.x); p1.y = f2bf_rne(v1.y);
    p1.z = f2bf_rne(v1.z); p1.w = f2bf_rne(v1.w);
    *(ushort4*)(Xb + (size_t)row * KDIM + lane * 4)       = p0;
    *(ushort4*)(Xb + (size_t)row * KDIM + 256 + lane * 4) = p1;

    float s2 = v0.x*v0.x + v0.y*v0.y + v0.z*v0.z + v0.w*v0.w
             + v1.x*v1.x + v1.y*v1.y + v1.z*v1.z + v1.w*v1.w;
    float rs = s2;
#pragma unroll
    for (int off = 32; off; off >>= 1) rs += __shfl_xor(rs, off, 64);
    if (lane == 0) sq[row] = rs;
    lss += s2;

    ca[0] += v0.x; ca[1] += v0.y; ca[2] += v0.z; ca[3] += v0.w;
    ca[4] += v1.x; ca[5] += v1.y; ca[6] += v1.z; ca[7] += v1.w;
  }

#pragma unroll
  for (int i = 0; i < 4; ++i) {
    ssv[w][lane * 4 + i]       = ca[i];
    ssv[w][256 + lane * 4 + i] = ca[4 + i];
  }
  float wsum = lss;
#pragma unroll
  for (int off = 32; off; off >>= 1) wsum += __shfl_xor(wsum, off, 64);
  if (lane == 0) ssq[w] = wsum;
  __syncthreads();

  svec_part[(size_t)b * 512 + tid] =
      ssv[0][tid] + ssv[1][tid] + ssv[2][tid] + ssv[3][tid];
  svec_part[(size_t)b * 512 + 256 + tid] =
      ssv[0][tid + 256] + ssv[1][tid + 256] + ssv[2][tid + 256] + ssv[3][tid + 256];
  if (tid == 0) sumsq_part[b] = ssq[0] + ssq[1] + ssq[2] + ssq[3];
}

// ---------------------------------------------------------------------------
// Kernel 2: sigma^2 = 2*sum(sq)/m - 2*||sum_i x_i||^2 / m^2 ; scale = log2e/(2s2)
// ---------------------------------------------------------------------------
__global__ __launch_bounds__(256) void k_sigma(
    const float* __restrict__ svec_part, const float* __restrict__ sumsq_part,
    float* __restrict__ scale) {
  __shared__ float red[4];
  const int tid = threadIdx.x, lane = tid & 63, w = tid >> 6;
  float s1 = 0.f, s2 = 0.f;
  for (int b = 0; b < 128; ++b) {
    s1 += svec_part[(size_t)b * 512 + tid];
    s2 += svec_part[(size_t)b * 512 + 256 + tid];
  }
  float ss = s1 * s1 + s2 * s2;
#pragma unroll
  for (int off = 32; off; off >>= 1) ss += __shfl_xor(ss, off, 64);
  if (lane == 0) red[w] = ss;
  __syncthreads();
  if (tid == 0) {
    float sst = red[0] + red[1] + red[2] + red[3];
    float sumsq = 0.f;
    for (int b = 0; b < 128; ++b) sumsq += sumsq_part[b];
    const float m = (float)MROWS;
    float meand2 = 2.f * sumsq / m - 2.f * sst / (m * m);
    float sigma2 = 1.0f * meand2;  // ALPHA = 1.0
    scale[0] = 1.4426950408889634f / (2.f * sigma2);
  }
}

// ---------------------------------------------------------------------------
// Kernel 3: tiled bf16 MFMA GEMM (gram = Xb * Xb^T) with fused epilogue.
// 128x128 tile, BK=64, 4 waves, DOUBLE-BUFFERED LDS: STAGE(next) issued
// before compute(cur); single __syncthreads per K-step (compiler emits
// vmcnt(0)+lgkmcnt(0) drain at the barrier -> m97/T3-minimum structure).
// ---------------------------------------------------------------------------
#define STAGE(buf, kt)                                                  \
  for (int c4 = 0; c4 < 4; ++c4) {                                      \
    const int chunk = w * 4 + c4;                                       \
    GL2LDS(baseA + (size_t)chunk * 8 * KDIM + (size_t)(kt) * 64,        \
           &As[buf][chunk * 512]);                                      \
    GL2LDS(baseB + (size_t)chunk * 8 * KDIM + (size_t)(kt) * 64,        \
           &Bs[buf][chunk * 512]);                                      \
  }

__global__ __launch_bounds__(256) void k_gemm(
    const unsigned short* __restrict__ Xb, const float* __restrict__ sq,
    const float* __restrict__ scale, float* __restrict__ out) {
  __shared__ unsigned short As[2][128 * 64];
  __shared__ unsigned short Bs[2][128 * 64];
  const int tid = threadIdx.x, lane = tid & 63, w = tid >> 6;

  // XCD-aware swizzle: nwg = 4096 (divisible by 8 -> bijective)
  int wg = blockIdx.x;
  wg = (wg & 7) * 512 + (wg >> 3);
  const int bi = wg >> 6, bj = wg & 63;
  const int wr = w >> 1, wc = w & 1;

  f32x4 acc[4][4] = {};

  const unsigned short* baseA =
      Xb + (size_t)(bi * 128 + (lane >> 3)) * KDIM + (lane & 7) * 8;
  const unsigned short* baseB =
      Xb + (size_t)(bj * 128 + (lane >> 3)) * KDIM + (lane & 7) * 8;

  STAGE(0, 0);
  __syncthreads();  // vmcnt(0) drained here by compiler

  int cur = 0;
#pragma unroll 1
  for (int kt = 0; kt < 8; ++kt) {
    if (kt < 7) { STAGE(cur ^ 1, kt + 1); }  // prefetch next K-tile

    const unsigned short* Ac = As[cur];
    const unsigned short* Bc = Bs[cur];
#pragma unroll
    for (int ks = 0; ks < 2; ++ks) {
      short8 a[4], b[4];
#pragma unroll
      for (int mm = 0; mm < 4; ++mm)
        a[mm] = *(const short8*)&Ac[(wr * 64 + mm * 16 + (lane & 15)) * 64 +
                                    ks * 32 + (lane >> 4) * 8];
#pragma unroll
      for (int n = 0; n < 4; ++n)
        b[n] = *(const short8*)&Bc[(wc * 64 + n * 16 + (lane & 15)) * 64 +
                                   ks * 32 + (lane >> 4) * 8];
#pragma unroll
      for (int mm = 0; mm < 4; ++mm)
#pragma unroll
        for (int n = 0; n < 4; ++n)
          acc[mm][n] = __builtin_amdgcn_mfma_f32_16x16x32_bf16(
              a[mm], b[n], acc[mm][n], 0, 0, 0);
    }
    __syncthreads();  // drains stage loads (vmcnt) + lds reads (lgkm)
    cur ^= 1;
  }

  // epilogue: out = exp2(-max(sq_i + sq_j - 2*gram, 0) * scale)
  const float cs = scale[0];
  const int r0 = bi * 128 + wr * 64 + (lane >> 4) * 4;
  const int c0 = bj * 128 + wc * 64 + (lane & 15);
  float srow[4][4];
#pragma unroll
  for (int mm = 0; mm < 4; ++mm)
#pragma unroll
    for (int r = 0; r < 4; ++r) srow[mm][r] = sq[r0 + mm * 16 + r];
  float scol[4];
#pragma unroll
  for (int n = 0; n < 4; ++n) scol[n] = sq[c0 + n * 16];

#pragma unroll
  for (int mm = 0; mm < 4; ++mm) {
#pragma unroll
    for (int r = 0; r < 4; ++r) {
      const size_t rowoff = (size_t)(r0 + mm * 16 + r) * MROWS;
#pragma unroll
      for (int n = 0; n < 4; ++n) {
        float d2 = srow[mm][r] + scol[n] - 2.f * acc[mm][n][r];
        d2 = fmaxf(d2, 0.f);
        out[rowoff + c0 + n * 16] = EXP2F(-d2 * cs);
      }
    }
  }
}

// ---------------------------------------------------------------------------
extern "C" void kernel_launch(void* const* d_in, const int* in_sizes, int n_in,
                              void* d_out, int out_size, void* d_ws,
                              size_t ws_size, hipStream_t stream) {
  (void)in_sizes; (void)n_in; (void)out_size; (void)ws_size;
  const float* X = (const float*)d_in[0];
  float* out = (float*)d_out;
  char* ws = (char*)d_ws;

  unsigned short* Xb  = (unsigned short*)ws;                     // 8 MB bf16
  float* sq           = (float*)(ws + 8388608);                  // 32 KB
  float* svec_part    = (float*)(ws + 8388608 + 32768);          // 256 KB
  float* sumsq_part   = (float*)(ws + 8388608 + 32768 + 262144); // 512 B
  float* scale        = (float*)(ws + 8388608 + 32768 + 262144 + 512);

  hipLaunchKernelGGL(k_prep, dim3(128), dim3(256), 0, stream,
                     X, Xb, sq, svec_part, sumsq_part);
  hipLaunchKernelGGL(k_sigma, dim3(1), dim3(256), 0, stream,
                     svec_part, sumsq_part, scale);
  hipLaunchKernelGGL(k_gemm, dim3(4096), dim3(256), 0, stream,
                     Xb, sq, scale, out);
}

// Round 4
// 134.297 us; speedup vs baseline: 1.2016x; 1.2016x over previous
//
#include <hip/hip_runtime.h>
#include <stdint.h>

#define MROWS 8192
#define KDIM  512

typedef __attribute__((ext_vector_type(8))) short short8;
typedef __attribute__((ext_vector_type(4))) float f32x4;

#if __has_builtin(__builtin_amdgcn_exp2f)
#define EXP2F(x) __builtin_amdgcn_exp2f(x)
#else
#define EXP2F(x) exp2f(x)
#endif

#define GL2LDS(gp, lp) __builtin_amdgcn_global_load_lds( \
    (__attribute__((address_space(1))) void*)(gp),       \
    (__attribute__((address_space(3))) void*)(lp), 16, 0, 0)

__device__ inline unsigned short f2bf_rne(float f) {
  unsigned u = __builtin_bit_cast(unsigned, f);
  unsigned r = 0x7FFFu + ((u >> 16) & 1u);
  return (unsigned short)((u + r) >> 16);
}

// Swizzle: logical (row, g) -> physical granule within a 1024-granule K-half.
// Verified bijective (validation passed in R2): swzP(row(P), gg(P)) == P.
__device__ inline int swzP(int row, int g) {
  return (row * 4) ^ (g ^ (row & 3)) ^ (((row >> 2) & 1) << 2);
}

// ---------------------------------------------------------------------------
// Kernel 1: cast X -> bf16, row norms, partial sums for sigma^2 (deterministic).
// ---------------------------------------------------------------------------
__global__ __launch_bounds__(256) void k_prep(
    const float* __restrict__ X, unsigned short* __restrict__ Xb,
    float* __restrict__ sq, float* __restrict__ svec_part,
    float* __restrict__ sumsq_part) {
  __shared__ float ssv[4][512];
  __shared__ float ssq[4];
  const int tid = threadIdx.x, lane = tid & 63, w = tid >> 6;
  const int b = blockIdx.x;

  float ca[8] = {0.f, 0.f, 0.f, 0.f, 0.f, 0.f, 0.f, 0.f};
  float lss = 0.f;

  for (int rr = 0; rr < 16; ++rr) {
    const int row = b * 64 + w * 16 + rr;
    const float4* xr = (const float4*)(X + (size_t)row * KDIM);
    float4 v0 = xr[lane];
    float4 v1 = xr[64 + lane];

    ushort4 p0, p1;
    p0.x = f2bf_rne(v0.x); p0.y = f2bf_rne(v0.y);
    p0.z = f2bf_rne(v0.z); p0.w = f2bf_rne(v0.w);
    p1.x = f2bf_rne(v1.x); p1.y = f2bf_rne(v1.y);
    p1.z = f2bf_rne(v1.z); p1.w = f2bf_rne(v1.w);
    *(ushort4*)(Xb + (size_t)row * KDIM + lane * 4)       = p0;
    *(ushort4*)(Xb + (size_t)row * KDIM + 256 + lane * 4) = p1;

    float s2 = v0.x*v0.x + v0.y*v0.y + v0.z*v0.z + v0.w*v0.w
             + v1.x*v1.x + v1.y*v1.y + v1.z*v1.z + v1.w*v1.w;
    float rs = s2;
#pragma unroll
    for (int off = 32; off; off >>= 1) rs += __shfl_xor(rs, off, 64);
    if (lane == 0) sq[row] = rs;
    lss += s2;

    ca[0] += v0.x; ca[1] += v0.y; ca[2] += v0.z; ca[3] += v0.w;
    ca[4] += v1.x; ca[5] += v1.y; ca[6] += v1.z; ca[7] += v1.w;
  }

#pragma unroll
  for (int i = 0; i < 4; ++i) {
    ssv[w][lane * 4 + i]       = ca[i];
    ssv[w][256 + lane * 4 + i] = ca[4 + i];
  }
  float wsum = lss;
#pragma unroll
  for (int off = 32; off; off >>= 1) wsum += __shfl_xor(wsum, off, 64);
  if (lane == 0) ssq[w] = wsum;
  __syncthreads();

  svec_part[(size_t)b * 512 + tid] =
      ssv[0][tid] + ssv[1][tid] + ssv[2][tid] + ssv[3][tid];
  svec_part[(size_t)b * 512 + 256 + tid] =
      ssv[0][tid + 256] + ssv[1][tid + 256] + ssv[2][tid + 256] + ssv[3][tid + 256];
  if (tid == 0) sumsq_part[b] = ssq[0] + ssq[1] + ssq[2] + ssq[3];
}

// ---------------------------------------------------------------------------
// Kernel 2: scale = log2e / (2*sigma^2)
// ---------------------------------------------------------------------------
__global__ __launch_bounds__(256) void k_sigma(
    const float* __restrict__ svec_part, const float* __restrict__ sumsq_part,
    float* __restrict__ scale) {
  __shared__ float red[4];
  const int tid = threadIdx.x, lane = tid & 63, w = tid >> 6;
  float s1 = 0.f, s2 = 0.f;
  for (int b = 0; b < 128; ++b) {
    s1 += svec_part[(size_t)b * 512 + tid];
    s2 += svec_part[(size_t)b * 512 + 256 + tid];
  }
  float ss = s1 * s1 + s2 * s2;
#pragma unroll
  for (int off = 32; off; off >>= 1) ss += __shfl_xor(ss, off, 64);
  if (lane == 0) red[w] = ss;
  __syncthreads();
  if (tid == 0) {
    float sst = red[0] + red[1] + red[2] + red[3];
    float sumsq = 0.f;
    for (int b = 0; b < 128; ++b) sumsq += sumsq_part[b];
    const float m = (float)MROWS;
    float meand2 = 2.f * sumsq / m - 2.f * sst / (m * m);
    float sigma2 = 1.0f * meand2;  // ALPHA = 1.0
    scale[0] = 1.4426950408889634f / (2.f * sigma2);
  }
}

// ---------------------------------------------------------------------------
// Kernel 3: 256x256-tile 8-phase bf16 MFMA GEMM.
// Sync rule (local, self-healing): per-phase s_waitcnt vmcnt(2) before the
// END barrier = "everything older than this phase's own 2 stage loads has
// drained". Inductively correct even if the compiler inserts extra VMEM ops
// (spills etc.) between counted loads. Min stage->read distance is 3 phases.
// ---------------------------------------------------------------------------
__global__ __launch_bounds__(512, 2) void k_gemm(
    const unsigned short* __restrict__ Xb, const float* __restrict__ sq,
    const float* __restrict__ scale, float* __restrict__ out) {
  __shared__ unsigned short As[2][16384];  // [buf][kh*8192 + granule*8]
  __shared__ unsigned short Bs[2][16384];
  const int tid = threadIdx.x, lane = tid & 63, w = tid >> 6;
  const int wr = w >> 2, wc = w & 3;  // 2 x 4 wave grid
  const int ln15 = lane & 15, g = lane >> 4;

  int blk = blockIdx.x;                    // 1024 blocks, %8==0 -> bijective
  int wg = (blk & 7) * 128 + (blk >> 3);
  const int bi = wg >> 5, bj = wg & 31;

  // stage-source: thread covers physical granules P = w*128 + q*64 + lane
  const unsigned short* XbA = Xb + (size_t)bi * 256 * KDIM;
  const unsigned short* XbB = Xb + (size_t)bj * 256 * KDIM;
  const unsigned short* sA[2];
  const unsigned short* sB[2];
  int dOf[2];
#pragma unroll
  for (int q = 0; q < 2; ++q) {
    const int P = (w << 7) + (q << 6) + lane;
    const int row = ((P >> 3) << 1) | (((P >> 2) ^ (P >> 4)) & 1);
    const int gg = (P & 3) ^ (row & 3);
    sA[q] = XbA + row * KDIM + gg * 8;
    sB[q] = XbB + row * KDIM + gg * 8;
    dOf[q] = (w << 10) + (q << 9);
  }

  // read-side swizzled element offsets within one K-half block
  int eaA[2][4], eaB[4];
#pragma unroll
  for (int mh = 0; mh < 2; ++mh)
#pragma unroll
    for (int m = 0; m < 4; ++m)
      eaA[mh][m] = swzP(wr * 128 + mh * 64 + m * 16 + ln15, g) * 8;
#pragma unroll
  for (int n = 0; n < 4; ++n)
    eaB[n] = swzP(wc * 64 + n * 16 + ln15, g) * 8;

  f32x4 acc[8][4] = {};
  short8 a[4], bfr[4];

#define STG_A(sb, kt, kh)                                                  \
  { GL2LDS(sA[0] + (kt) * 64 + (kh) * 32, &As[sb][(kh) * 8192 + dOf[0]]); \
    GL2LDS(sA[1] + (kt) * 64 + (kh) * 32, &As[sb][(kh) * 8192 + dOf[1]]); }
#define STG_B(sb, kt, kh)                                                  \
  { GL2LDS(sB[0] + (kt) * 64 + (kh) * 32, &Bs[sb][(kh) * 8192 + dOf[0]]); \
    GL2LDS(sB[1] + (kt) * 64 + (kh) * 32, &Bs[sb][(kh) * 8192 + dOf[1]]); }

  // prologue: Kt0 -> buf0, full drain (cheap, once)
  STG_A(0, 0, 0); STG_B(0, 0, 0); STG_A(0, 0, 1); STG_B(0, 0, 1);
  asm volatile("s_waitcnt vmcnt(0)" ::: "memory");
  __builtin_amdgcn_s_barrier();
  __builtin_amdgcn_sched_barrier(0);

#pragma unroll
  for (int i = 0; i < 4; ++i) {
#pragma unroll
    for (int p = 0; p < 8; ++p) {
      const int rb = (p < 4) ? 0 : 1;      // read buffer
      const int kh = (p >> 1) & 1;         // K-half being computed
      const int mh = p & 1;                // M-half quadrant

      // ds reads for this phase (data guaranteed: staged >=3 phases ago,
      // drained by the END-of-previous-phase vmcnt rule)
#pragma unroll
      for (int m = 0; m < 4; ++m)
        a[m] = *(const short8*)&As[rb][kh * 8192 + eaA[mh][m]];
      if (mh == 0) {
#pragma unroll
        for (int n = 0; n < 4; ++n)
          bfr[n] = *(const short8*)&Bs[rb][kh * 8192 + eaB[n]];
      }

      // stage exactly 1 half-tile (2 loads/thread) into the other buffer
      const int skt = (p < 4) ? (2 * i + 1) : (2 * i + 2);
      if (skt < 8) {
        const int sb = skt & 1;
        const int half = p & 3;  // 0:A-kh0 1:B-kh0 2:A-kh1 3:B-kh1
        if (half == 0)      STG_A(sb, skt, 0)
        else if (half == 1) STG_B(sb, skt, 0)
        else if (half == 2) STG_A(sb, skt, 1)
        else                STG_B(sb, skt, 1)
      }

      __builtin_amdgcn_s_barrier();        // MID
      asm volatile("s_waitcnt lgkmcnt(0)" ::: "memory");
      __builtin_amdgcn_sched_barrier(0);

      __builtin_amdgcn_s_setprio(1);
#pragma unroll
      for (int m = 0; m < 4; ++m)
#pragma unroll
        for (int n = 0; n < 4; ++n)
          acc[mh * 4 + m][n] = __builtin_amdgcn_mfma_f32_16x16x32_bf16(
              a[m], bfr[n], acc[mh * 4 + m][n], 0, 0, 0);
      __builtin_amdgcn_s_setprio(0);

      // local self-healing wait: drain everything older than this phase's loads
      if (skt < 8) {
        asm volatile("s_waitcnt vmcnt(2)" ::: "memory");
      } else if (p == 4) {                 // i==3 tail: drain the last stages
        asm volatile("s_waitcnt vmcnt(0)" ::: "memory");
      }
      __builtin_amdgcn_s_barrier();        // END
      __builtin_amdgcn_sched_barrier(0);
    }
  }

  asm volatile("s_waitcnt vmcnt(0) lgkmcnt(0)" ::: "memory");

  // epilogue: out = exp2(-max(sq_i + sq_j - 2*gram, 0) * scale)
  const float cs = scale[0];
  const int hi4 = (lane >> 4) * 4;
  const int rbase = bi * 256 + wr * 128 + hi4;
  const int cbase = bj * 256 + wc * 64 + ln15;

  float scol[4];
#pragma unroll
  for (int n = 0; n < 4; ++n) scol[n] = sq[cbase + n * 16];

#pragma unroll
  for (int mf = 0; mf < 8; ++mf) {
#pragma unroll
    for (int r = 0; r < 4; ++r) {
      const int row = rbase + mf * 16 + r;
      const float sr = sq[row];
      const size_t rowoff = (size_t)row * MROWS;
#pragma unroll
      for (int n = 0; n < 4; ++n) {
        float d2 = sr + scol[n] - 2.f * acc[mf][n][r];
        d2 = fmaxf(d2, 0.f);
        out[rowoff + cbase + n * 16] = EXP2F(-d2 * cs);
      }
    }
  }
}

// ---------------------------------------------------------------------------
extern "C" void kernel_launch(void* const* d_in, const int* in_sizes, int n_in,
                              void* d_out, int out_size, void* d_ws,
                              size_t ws_size, hipStream_t stream) {
  (void)in_sizes; (void)n_in; (void)out_size; (void)ws_size;
  const float* X = (const float*)d_in[0];
  float* out = (float*)d_out;
  char* ws = (char*)d_ws;

  unsigned short* Xb  = (unsigned short*)ws;                     // 8 MB bf16
  float* sq           = (float*)(ws + 8388608);                  // 32 KB
  float* svec_part    = (float*)(ws + 8388608 + 32768);          // 256 KB
  float* sumsq_part   = (float*)(ws + 8388608 + 32768 + 262144); // 512 B
  float* scale        = (float*)(ws + 8388608 + 32768 + 262144 + 512);

  hipLaunchKernelGGL(k_prep, dim3(128), dim3(256), 0, stream,
                     X, Xb, sq, svec_part, sumsq_part);
  hipLaunchKernelGGL(k_sigma, dim3(1), dim3(256), 0, stream,
                     svec_part, sumsq_part, scale);
  hipLaunchKernelGGL(k_gemm, dim3(1024), dim3(512), 0, stream,
                     Xb, sq, scale, out);
}

// Round 5
// 119.378 us; speedup vs baseline: 1.3518x; 1.1250x over previous
//
#include <hip/hip_runtime.h>
#include <stdint.h>
#include <math.h>

#define MROWS 8192
#define KDIM  512

typedef __attribute__((ext_vector_type(8))) short short8;
typedef __attribute__((ext_vector_type(4))) float f32x4;

#if __has_builtin(__builtin_amdgcn_exp2f)
#define EXP2F(x) __builtin_amdgcn_exp2f(x)
#else
#define EXP2F(x) exp2f(x)
#endif

#define GL2LDS(gp, lp) __builtin_amdgcn_global_load_lds( \
    (__attribute__((address_space(1))) void*)(gp),       \
    (__attribute__((address_space(3))) void*)(lp), 16, 0, 0)

__device__ inline unsigned short f2bf_rne(float f) {
  unsigned u = __builtin_bit_cast(unsigned, f);
  unsigned r = 0x7FFFu + ((u >> 16) & 1u);
  return (unsigned short)((u + r) >> 16);
}

// Swizzle: logical (row, g) -> physical granule within a 1024-granule K-half.
// Verified bijective on-device (R2/R3 validation).
__device__ inline int swzP(int row, int g) {
  return (row * 4) ^ (g ^ (row & 3)) ^ (((row >> 2) & 1) << 2);
}

// ---------------------------------------------------------------------------
// Kernel 1: cast X -> bf16, row norms, partial sums for sigma^2.
// 256 blocks x 256 threads; block handles 32 rows (wave: 8 rows).
// ---------------------------------------------------------------------------
__global__ __launch_bounds__(256) void k_prep(
    const float* __restrict__ X, unsigned short* __restrict__ Xb,
    float* __restrict__ sq, float* __restrict__ svec_part,
    float* __restrict__ sumsq_part) {
  __shared__ float ssv[4][512];
  __shared__ float ssq[4];
  const int tid = threadIdx.x, lane = tid & 63, w = tid >> 6;
  const int b = blockIdx.x;

  float ca[8] = {0.f, 0.f, 0.f, 0.f, 0.f, 0.f, 0.f, 0.f};
  float lss = 0.f;

  for (int rr = 0; rr < 8; ++rr) {
    const int row = b * 32 + w * 8 + rr;
    const float4* xr = (const float4*)(X + (size_t)row * KDIM);
    float4 v0 = xr[lane];
    float4 v1 = xr[64 + lane];

    ushort4 p0, p1;
    p0.x = f2bf_rne(v0.x); p0.y = f2bf_rne(v0.y);
    p0.z = f2bf_rne(v0.z); p0.w = f2bf_rne(v0.w);
    p1.x = f2bf_rne(v1.x); p1.y = f2bf_rne(v1.y);
    p1.z = f2bf_rne(v1.z); p1.w = f2bf_rne(v1.w);
    *(ushort4*)(Xb + (size_t)row * KDIM + lane * 4)       = p0;
    *(ushort4*)(Xb + (size_t)row * KDIM + 256 + lane * 4) = p1;

    float s2 = v0.x*v0.x + v0.y*v0.y + v0.z*v0.z + v0.w*v0.w
             + v1.x*v1.x + v1.y*v1.y + v1.z*v1.z + v1.w*v1.w;
    float rs = s2;
#pragma unroll
    for (int off = 32; off; off >>= 1) rs += __shfl_xor(rs, off, 64);
    if (lane == 0) sq[row] = rs;
    lss += s2;

    ca[0] += v0.x; ca[1] += v0.y; ca[2] += v0.z; ca[3] += v0.w;
    ca[4] += v1.x; ca[5] += v1.y; ca[6] += v1.z; ca[7] += v1.w;
  }

#pragma unroll
  for (int i = 0; i < 4; ++i) {
    ssv[w][lane * 4 + i]       = ca[i];
    ssv[w][256 + lane * 4 + i] = ca[4 + i];
  }
  float wsum = lss;
#pragma unroll
  for (int off = 32; off; off >>= 1) wsum += __shfl_xor(wsum, off, 64);
  if (lane == 0) ssq[w] = wsum;
  __syncthreads();

  svec_part[(size_t)b * 512 + tid] =
      ssv[0][tid] + ssv[1][tid] + ssv[2][tid] + ssv[3][tid];
  svec_part[(size_t)b * 512 + 256 + tid] =
      ssv[0][tid + 256] + ssv[1][tid + 256] + ssv[2][tid + 256] + ssv[3][tid + 256];
  if (tid == 0) sumsq_part[b] = ssq[0] + ssq[1] + ssq[2] + ssq[3];
}

// ---------------------------------------------------------------------------
// Kernel 2: scale = log2e / (2*sigma^2)
// ---------------------------------------------------------------------------
__global__ __launch_bounds__(256) void k_sigma(
    const float* __restrict__ svec_part, const float* __restrict__ sumsq_part,
    float* __restrict__ scale) {
  __shared__ float red[4];
  const int tid = threadIdx.x, lane = tid & 63, w = tid >> 6;
  float s1 = 0.f, s2 = 0.f;
  for (int b = 0; b < 256; ++b) {
    s1 += svec_part[(size_t)b * 512 + tid];
    s2 += svec_part[(size_t)b * 512 + 256 + tid];
  }
  float ss = s1 * s1 + s2 * s2;
#pragma unroll
  for (int off = 32; off; off >>= 1) ss += __shfl_xor(ss, off, 64);
  if (lane == 0) red[w] = ss;
  __syncthreads();
  if (tid == 0) {
    float sst = red[0] + red[1] + red[2] + red[3];
    float sumsq = 0.f;
    for (int b = 0; b < 256; ++b) sumsq += sumsq_part[b];
    const float m = (float)MROWS;
    float meand2 = 2.f * sumsq / m - 2.f * sst / (m * m);
    float sigma2 = 1.0f * meand2;  // ALPHA = 1.0
    scale[0] = 1.4426950408889634f / (2.f * sigma2);
  }
}

// ---------------------------------------------------------------------------
// Kernel 3: SYMMETRIC 256x256-tile 8-phase bf16 MFMA GEMM (loop = R3, proven).
// Grid = 528 upper-triangular tile pairs (bi <= bj). Off-diagonal blocks also
// write the transposed tile via LDS bounce (reusing the loop's 128 KB LDS).
// ---------------------------------------------------------------------------
__global__ __launch_bounds__(512, 2) void k_gemm(
    const unsigned short* __restrict__ Xb, const float* __restrict__ sq,
    const float* __restrict__ scale, float* __restrict__ out) {
  __shared__ __align__(16) char smem[131072];
  unsigned short* Asm = (unsigned short*)smem;          // As[sb][16384]
  unsigned short* Bsm = (unsigned short*)(smem + 65536);
  float* tr = (float*)smem;                             // epilogue transpose

  const int tid = threadIdx.x, lane = tid & 63, w = tid >> 6;
  const int wr = w >> 2, wc = w & 3;  // 2 x 4 wave grid
  const int ln15 = lane & 15, g = lane >> 4;

  // Upper-triangular unranking with XCD swizzle (528 = 8*66, bijective)
  const int blk = blockIdx.x;
  const int t = (blk & 7) * 66 + (blk >> 3);
  int j = (int)((sqrtf(8.0f * (float)t + 1.0f) - 1.0f) * 0.5f);
  while ((j + 1) * (j + 2) / 2 <= t) ++j;
  while (j * (j + 1) / 2 > t) --j;
  const int bi = t - j * (j + 1) / 2;  // bi <= bj
  const int bj = j;

  // stage-source: thread covers physical granules P = w*128 + q*64 + lane
  const unsigned short* XbA = Xb + (size_t)bi * 256 * KDIM;
  const unsigned short* XbB = Xb + (size_t)bj * 256 * KDIM;
  const unsigned short* sA[2];
  const unsigned short* sB[2];
  int dOf[2];
#pragma unroll
  for (int q = 0; q < 2; ++q) {
    const int P = (w << 7) + (q << 6) + lane;
    const int row = ((P >> 3) << 1) | (((P >> 2) ^ (P >> 4)) & 1);
    const int gg = (P & 3) ^ (row & 3);
    sA[q] = XbA + row * KDIM + gg * 8;
    sB[q] = XbB + row * KDIM + gg * 8;
    dOf[q] = (w << 10) + (q << 9);
  }

  // read-side swizzled element offsets within one K-half block
  int eaA[2][4], eaB[4];
#pragma unroll
  for (int mh = 0; mh < 2; ++mh)
#pragma unroll
    for (int m = 0; m < 4; ++m)
      eaA[mh][m] = swzP(wr * 128 + mh * 64 + m * 16 + ln15, g) * 8;
#pragma unroll
  for (int n = 0; n < 4; ++n)
    eaB[n] = swzP(wc * 64 + n * 16 + ln15, g) * 8;

  f32x4 acc[8][4] = {};
  short8 a[4], bfr[4];

#define STG_A(sb, kt, kh)                                                      \
  { GL2LDS(sA[0] + (kt) * 64 + (kh) * 32, &Asm[(sb)*16384 + (kh)*8192 + dOf[0]]); \
    GL2LDS(sA[1] + (kt) * 64 + (kh) * 32, &Asm[(sb)*16384 + (kh)*8192 + dOf[1]]); }
#define STG_B(sb, kt, kh)                                                      \
  { GL2LDS(sB[0] + (kt) * 64 + (kh) * 32, &Bsm[(sb)*16384 + (kh)*8192 + dOf[0]]); \
    GL2LDS(sB[1] + (kt) * 64 + (kh) * 32, &Bsm[(sb)*16384 + (kh)*8192 + dOf[1]]); }

  // prologue: Kt0 -> buf0, full drain
  STG_A(0, 0, 0); STG_B(0, 0, 0); STG_A(0, 0, 1); STG_B(0, 0, 1);
  asm volatile("s_waitcnt vmcnt(0)" ::: "memory");
  __builtin_amdgcn_s_barrier();
  __builtin_amdgcn_sched_barrier(0);

#pragma unroll
  for (int i = 0; i < 4; ++i) {
#pragma unroll
    for (int p = 0; p < 8; ++p) {
      const int rb = (p < 4) ? 0 : 1;      // read buffer
      const int kh = (p >> 1) & 1;         // K-half being computed
      const int mh = p & 1;                // M-half quadrant

#pragma unroll
      for (int m = 0; m < 4; ++m)
        a[m] = *(const short8*)&Asm[rb * 16384 + kh * 8192 + eaA[mh][m]];
      if (mh == 0) {
#pragma unroll
        for (int n = 0; n < 4; ++n)
          bfr[n] = *(const short8*)&Bsm[rb * 16384 + kh * 8192 + eaB[n]];
      }

      // stage exactly 1 half-tile (2 loads/thread) into the other buffer
      const int skt = (p < 4) ? (2 * i + 1) : (2 * i + 2);
      if (skt < 8) {
        const int sb = skt & 1;
        const int half = p & 3;  // 0:A-kh0 1:B-kh0 2:A-kh1 3:B-kh1
        if (half == 0)      STG_A(sb, skt, 0)
        else if (half == 1) STG_B(sb, skt, 0)
        else if (half == 2) STG_A(sb, skt, 1)
        else                STG_B(sb, skt, 1)
      }

      __builtin_amdgcn_s_barrier();        // MID
      asm volatile("s_waitcnt lgkmcnt(0)" ::: "memory");
      __builtin_amdgcn_sched_barrier(0);

      __builtin_amdgcn_s_setprio(1);
#pragma unroll
      for (int m = 0; m < 4; ++m)
#pragma unroll
        for (int n = 0; n < 4; ++n)
          acc[mh * 4 + m][n] = __builtin_amdgcn_mfma_f32_16x16x32_bf16(
              a[m], bfr[n], acc[mh * 4 + m][n], 0, 0, 0);
      __builtin_amdgcn_s_setprio(0);

      // local self-healing wait (drain everything older than this phase's loads)
      if (skt < 8) {
        asm volatile("s_waitcnt vmcnt(2)" ::: "memory");
      } else if (p == 4) {
        asm volatile("s_waitcnt vmcnt(0)" ::: "memory");
      }
      __builtin_amdgcn_s_barrier();        // END
      __builtin_amdgcn_sched_barrier(0);
    }
  }

  asm volatile("s_waitcnt vmcnt(0) lgkmcnt(0)" ::: "memory");

  // ---- epilogue 1: exp2 in place + direct stores of tile (bi, bj)
  const float cs = scale[0];
  const int hi4 = (lane >> 4) * 4;
  const int rbase = bi * 256 + wr * 128 + hi4;
  const int cbase = bj * 256 + wc * 64 + ln15;

  float scol[4];
#pragma unroll
  for (int n = 0; n < 4; ++n) scol[n] = sq[cbase + n * 16];

#pragma unroll
  for (int mf = 0; mf < 8; ++mf) {
#pragma unroll
    for (int r = 0; r < 4; ++r) {
      const int row = rbase + mf * 16 + r;
      const float sr = sq[row];
      const size_t rowoff = (size_t)row * MROWS;
#pragma unroll
      for (int n = 0; n < 4; ++n) {
        float d2 = sr + scol[n] - 2.f * acc[mf][n][r];
        d2 = fmaxf(d2, 0.f);
        float v = EXP2F(-d2 * cs);
        acc[mf][n][r] = v;  // keep for transposed store
        out[rowoff + cbase + n * 16] = v;
      }
    }
  }

  // ---- epilogue 2: transposed tile (bj, bi) via LDS bounce (off-diag only)
  if (bi != bj) {
#pragma unroll 1
    for (int cc = 0; cc < 4; ++cc) {
      __syncthreads();  // LDS reuse safe: after loop END barrier / prev reads
      if (wc == cc) {   // the 2 waves owning this 64-col chunk write it
#pragma unroll
        for (int mf = 0; mf < 8; ++mf) {
#pragma unroll
          for (int n = 0; n < 4; ++n) {
            const int c_loc = n * 16 + ln15;          // 0..63
            const int r_loc = wr * 128 + mf * 16 + hi4;  // 0..255, %4==0
            *(float4*)&tr[c_loc * 260 + r_loc] = *(float4*)&acc[mf][n];
          }
        }
      }
      __syncthreads();
      // all 8 waves: each handles 8 of the 64 chunk-columns as output rows
#pragma unroll
      for (int rr = 0; rr < 8; ++rr) {
        const int row = w * 8 + rr;                   // c_loc
        float4 v = *(const float4*)&tr[row * 260 + lane * 4];
        *(float4*)&out[(size_t)(bj * 256 + cc * 64 + row) * MROWS +
                       bi * 256 + lane * 4] = v;
      }
    }
  }
}

// ---------------------------------------------------------------------------
extern "C" void kernel_launch(void* const* d_in, const int* in_sizes, int n_in,
                              void* d_out, int out_size, void* d_ws,
                              size_t ws_size, hipStream_t stream) {
  (void)in_sizes; (void)n_in; (void)out_size; (void)ws_size;
  const float* X = (const float*)d_in[0];
  float* out = (float*)d_out;
  char* ws = (char*)d_ws;

  unsigned short* Xb  = (unsigned short*)ws;                      // 8 MB bf16
  float* sq           = (float*)(ws + 8388608);                   // 32 KB
  float* svec_part    = (float*)(ws + 8388608 + 32768);           // 512 KB
  float* sumsq_part   = (float*)(ws + 8388608 + 32768 + 524288);  // 1 KB
  float* scale        = (float*)(ws + 8388608 + 32768 + 524288 + 1024);

  hipLaunchKernelGGL(k_prep, dim3(256), dim3(256), 0, stream,
                     X, Xb, sq, svec_part, sumsq_part);
  hipLaunchKernelGGL(k_sigma, dim3(1), dim3(256), 0, stream,
                     svec_part, sumsq_part, scale);
  hipLaunchKernelGGL(k_gemm, dim3(528), dim3(512), 0, stream,
                     Xb, sq, scale, out);
}